// Round 6
// baseline (747.676 us; speedup 1.0000x reference)
//
#include <hip/hip_runtime.h>
#include <stdint.h>

#define B_ 32
#define T_ 2048
#define C_ 768
#define H_ 1536
#define L_ 16

typedef unsigned short u16;
typedef __bf16 bf16x8 __attribute__((ext_vector_type(8)));
typedef float f32x4 __attribute__((ext_vector_type(4)));

__device__ __forceinline__ u16 f2bf(float f) {
    union { float f; uint32_t u; } v; v.f = f;
    uint32_t r = (v.u + 0x7fffu + ((v.u >> 16) & 1u)) >> 16;
    return (u16)r;
}

__device__ __forceinline__ float wave_sum(float v) {
    v += __shfl_xor(v, 1);  v += __shfl_xor(v, 2);  v += __shfl_xor(v, 4);
    v += __shfl_xor(v, 8);  v += __shfl_xor(v, 16); v += __shfl_xor(v, 32);
    return v;
}

__global__ void k_cvt(const float* __restrict__ in, u16* __restrict__ out, int n4) {
    int stride = gridDim.x * blockDim.x;
    for (int i = blockIdx.x * blockDim.x + threadIdx.x; i < n4; i += stride) {
        float4 v = reinterpret_cast<const float4*>(in)[i];
        ushort4 o;
        o.x = f2bf(v.x); o.y = f2bf(v.y); o.z = f2bf(v.z); o.w = f2bf(v.w);
        reinterpret_cast<ushort4*>(out)[i] = o;
    }
}

__device__ __forceinline__ void gload16(const u16* g, u16* l) {
    __builtin_amdgcn_global_load_lds((const __attribute__((address_space(1))) void*)g,
                                     (__attribute__((address_space(3))) void*)l, 16, 0, 0);
}

// ======= 256x256 bf16 GEMM, 2-region K-tile, fused fp32->bf16 staging =======
// One operand G (bf16) staged via global_load_lds; one operand F (fp32) staged
// via reg: issue dwordx4 early -> counted vmcnt -> cvt -> swizzled ds_write.
// EPI 0: F=A=x, G=B=Wqb; out = A@B^T+bias -> bf16 qout.
// EPI 1: G=A=qb, F=B=W0; silu(A@B^T+bias), window-mean -> ph.
template <int EPI>
__global__ __launch_bounds__(512, 2) void k_gemmF(const u16* __restrict__ Gsrc,
                                                  const float* __restrict__ Fsrc,
                                                  const float* __restrict__ biasall,
                                                  u16* __restrict__ qout,
                                                  float* __restrict__ ph) {
    __shared__ u16 sm[65536];   // [buf2][A/B][half2][128*64] = 128 KiB
    const int t = threadIdx.x;
    const int w = t >> 6, lane = t & 63;
    const int wr = w >> 2, wc = w & 3;
    const int l15 = lane & 15, kq = lane >> 4, cx = lane & 7;

    // T1: bijective XCD-aware block remap (nwg % 8 == 0 for both EPIs)
    const int gx = gridDim.x, gy = gridDim.y;
    const int nwg = gx * gy * gridDim.z;
    int flat = blockIdx.x + gx * (blockIdx.y + gy * blockIdx.z);
    if ((nwg & 7) == 0) flat = (flat & 7) * (nwg >> 3) + (flat >> 3);
    const int bx = flat % gx;
    const int tmp = flat / gx;
    const int by = tmp % gy;
    const int bz = tmp / gy;

    const int n0 = bx * 256;
    const int m0 = by * 256;
    const u16* Gbase; const float* Fbase; const float* bias;
    int Goff, Foff;
    if constexpr (EPI == 0) {
        Fbase = Fsrc + (size_t)m0 * C_;            Foff = 0;      // A = x (fp32)
        Gbase = Gsrc + (size_t)n0 * C_;            Goff = 16384;  // B = Wqb
        bias  = biasall + n0;
    } else {
        Gbase = Gsrc + ((size_t)bz * T_ + m0) * C_; Goff = 0;     // A = qb
        Fbase = Fsrc + ((size_t)bz * H_ + n0) * C_; Foff = 16384; // B = W0 (fp32)
        bias  = biasall + (size_t)bz * H_ + n0;
    }

    // ---- G staging (gload_lds): wave w covers rows [w*16, w*16+16) per half ----
    const int rl = (w << 4) + (lane >> 3);
    const int cs = (((lane & 7) ^ ((lane >> 3) & 7)) << 3);
    const int ldst = (w << 10);
    auto stG = [&](int kt, int h) {
        const u16* g = Gbase + (size_t)(h * 128 + rl) * C_ + kt * 64 + cs;
        u16* l = sm + (kt & 1) * 32768 + Goff + h * 8192 + ldst;
        gload16(g, l);
        gload16(g + 8 * C_, l + 512);
    };

    // ---- F staging (reg + cvt + swizzled ds_write) ----
    // thread t: row-in-passgroup fr=t>>4, float4-col fc=t&15; pass p covers
    // rows b*128 + p*32 + fr. Swizzled chunk = (fc>>1) ^ (fr&7) (p*32%8==0).
    const int fr = t >> 4;
    const int fc = t & 15;
    const int fswz = ((fc >> 1) ^ (fr & 7));
    const int fsub = (fc & 1) * 4;
    float4 fg0[4], fg1[4];
    auto fissue = [&](int kt, int b, float4 (&fregs)[4]) {
#pragma unroll
        for (int p = 0; p < 4; ++p)
            fregs[p] = *reinterpret_cast<const float4*>(
                Fbase + (size_t)(b * 128 + p * 32 + fr) * C_ + kt * 64 + fc * 4);
    };
    auto fwrite = [&](int bdst, int b, float4 (&fregs)[4]) {
        u16* base = sm + Foff + bdst * 32768 + b * 8192 + fr * 64 + fswz * 8 + fsub;
#pragma unroll
        for (int p = 0; p < 4; ++p) {
            ushort4 o;
            o.x = f2bf(fregs[p].x); o.y = f2bf(fregs[p].y);
            o.z = f2bf(fregs[p].z); o.w = f2bf(fregs[p].w);
            *reinterpret_cast<ushort4*>(base + p * 2048) = o;
        }
    };

    f32x4 acc[8][4];
#pragma unroll
    for (int m = 0; m < 8; ++m)
#pragma unroll
        for (int n = 0; n < 4; ++n) acc[m][n] = (f32x4){0.f, 0.f, 0.f, 0.f};

    bf16x8 a0[4][2], a1[4][2], bfr[2][2];

    // per-lane LDS read bases; in-loop reads are base + literal offsets
    const int koff0 = ((kq ^ cx) << 3);
    const int koff1 = (((4 + kq) ^ cx) << 3);
    const u16* vA0 = sm + wr * 8192 + l15 * 64 + koff0;
    const u16* vA1 = sm + wr * 8192 + l15 * 64 + koff1;
    const u16* vB0 = sm + 16384 + (wc >> 1) * 8192 + (wc & 1) * 4096 + l15 * 64 + koff0;
    const u16* vB1 = sm + 16384 + (wc >> 1) * 8192 + (wc & 1) * 4096 + l15 * 64 + koff1;

    auto rdAB0 = [&](int bt) {
        const u16* A0 = vA0 + bt * 32768;
        const u16* A1 = vA1 + bt * 32768;
        const u16* B0 = vB0 + bt * 32768;
        const u16* B1 = vB1 + bt * 32768;
        bfr[0][0] = *reinterpret_cast<const bf16x8*>(B0);
        bfr[1][0] = *reinterpret_cast<const bf16x8*>(B0 + 1024);
        a0[0][0] = *reinterpret_cast<const bf16x8*>(A0);
        a0[1][0] = *reinterpret_cast<const bf16x8*>(A0 + 1024);
        a0[2][0] = *reinterpret_cast<const bf16x8*>(A0 + 2048);
        a0[3][0] = *reinterpret_cast<const bf16x8*>(A0 + 3072);
        bfr[0][1] = *reinterpret_cast<const bf16x8*>(B1);
        bfr[1][1] = *reinterpret_cast<const bf16x8*>(B1 + 1024);
        a0[0][1] = *reinterpret_cast<const bf16x8*>(A1);
        a0[1][1] = *reinterpret_cast<const bf16x8*>(A1 + 1024);
        a0[2][1] = *reinterpret_cast<const bf16x8*>(A1 + 2048);
        a0[3][1] = *reinterpret_cast<const bf16x8*>(A1 + 3072);
    };
    auto rdA1 = [&](int bt) {
        const u16* A0 = vA0 + bt * 32768 + 4096;
        const u16* A1 = vA1 + bt * 32768 + 4096;
        a1[0][0] = *reinterpret_cast<const bf16x8*>(A0);
        a1[1][0] = *reinterpret_cast<const bf16x8*>(A0 + 1024);
        a1[2][0] = *reinterpret_cast<const bf16x8*>(A0 + 2048);
        a1[3][0] = *reinterpret_cast<const bf16x8*>(A0 + 3072);
        a1[0][1] = *reinterpret_cast<const bf16x8*>(A1);
        a1[1][1] = *reinterpret_cast<const bf16x8*>(A1 + 1024);
        a1[2][1] = *reinterpret_cast<const bf16x8*>(A1 + 2048);
        a1[3][1] = *reinterpret_cast<const bf16x8*>(A1 + 3072);
    };
    auto rdB1 = [&](int bt) {
        const u16* B0 = vB0 + bt * 32768 + 2048;
        const u16* B1 = vB1 + bt * 32768 + 2048;
        bfr[0][0] = *reinterpret_cast<const bf16x8*>(B0);
        bfr[1][0] = *reinterpret_cast<const bf16x8*>(B0 + 1024);
        bfr[0][1] = *reinterpret_cast<const bf16x8*>(B1);
        bfr[1][1] = *reinterpret_cast<const bf16x8*>(B1 + 1024);
    };
    auto mma16 = [&](bf16x8 (&a)[4][2], int mq, int qn) {
        __builtin_amdgcn_s_setprio(1);
#pragma unroll
        for (int ks = 0; ks < 2; ++ks)
#pragma unroll
            for (int mm = 0; mm < 4; ++mm)
#pragma unroll
                for (int nn = 0; nn < 2; ++nn)
                    acc[mq * 4 + mm][qn * 2 + nn] = __builtin_amdgcn_mfma_f32_16x16x32_bf16(
                        a[mm][ks], bfr[nn][ks], acc[mq * 4 + mm][qn * 2 + nn], 0, 0, 0);
        __builtin_amdgcn_s_setprio(0);
    };

    // ---- prologue: stage tile 0 into buf 0 ----
    fissue(0, 0, fg0);
    fissue(0, 1, fg1);
    stG(0, 0); stG(0, 1);
    asm volatile("s_waitcnt vmcnt(8)" ::: "memory");   // fg0 landed
    fwrite(0, 0, fg0);
    asm volatile("s_waitcnt vmcnt(4)" ::: "memory");   // fg1 landed
    fwrite(0, 1, fg1);
    asm volatile("s_waitcnt lgkmcnt(0)" ::: "memory"); // writes retired
    asm volatile("s_waitcnt vmcnt(0)" ::: "memory");   // G landed
    __builtin_amdgcn_sched_barrier(0);
    __builtin_amdgcn_s_barrier();

    auto ktile = [&](int kt, int bt) {
        const bool nx = (kt + 1 < 12);
        // R1: F(kt+1) b0 issue | frags a0,a1,bfr(qn0) | mma | F b1 + G issue | mma
        if (nx) fissue(kt + 1, 0, fg0);
        rdAB0(bt);
        rdA1(bt);
        mma16(a0, 0, 0);
        if (nx) {
            fissue(kt + 1, 1, fg1);
            stG(kt + 1, 0); stG(kt + 1, 1);
        }
        mma16(a1, 1, 0);
        asm volatile("s_waitcnt vmcnt(8)" ::: "memory");  // fg0 landed
        if (nx) fwrite(bt ^ 1, 0, fg0);
        __builtin_amdgcn_sched_barrier(0);
        __builtin_amdgcn_s_barrier();
        // R2: frags bfr(qn1) | mma | fg1 cvt+write | publish | G landed
        rdB1(bt);
        mma16(a0, 0, 1);
        mma16(a1, 1, 1);
        asm volatile("s_waitcnt vmcnt(4)" ::: "memory");  // fg1 landed
        if (nx) fwrite(bt ^ 1, 1, fg1);
        asm volatile("s_waitcnt lgkmcnt(0)" ::: "memory"); // writes published
        asm volatile("s_waitcnt vmcnt(0)" ::: "memory");   // G(kt+1) landed
        __builtin_amdgcn_sched_barrier(0);
        __builtin_amdgcn_s_barrier();
    };

#pragma unroll 1
    for (int ktb = 0; ktb < 12; ktb += 2) {
        ktile(ktb, 0);
        ktile(ktb + 1, 1);
    }

    if constexpr (EPI == 0) {
        const int colb = n0 + wc * 64 + l15;
        const int rowb = m0 + wr * 128 + (kq << 2);
        float bv[4];
#pragma unroll
        for (int n = 0; n < 4; ++n) bv[n] = bias[wc * 64 + n * 16 + l15];
#pragma unroll
        for (int m = 0; m < 8; ++m)
#pragma unroll
            for (int r = 0; r < 4; ++r) {
                size_t ro = (size_t)(rowb + m * 16 + r) * C_;
#pragma unroll
                for (int n = 0; n < 4; ++n)
                    qout[ro + colb + n * 16] = f2bf(acc[m][n][r] + bv[n]);
            }
    } else {
        const int lwin = by * 2 + wr;   // wave's 128 rows == one pooling window
#pragma unroll
        for (int n = 0; n < 4; ++n) {
            int cloc = wc * 64 + n * 16 + l15;
            float bv = bias[cloc];
            float s = 0.f;
#pragma unroll
            for (int m = 0; m < 8; ++m)
#pragma unroll
                for (int r = 0; r < 4; ++r) {
                    float v = acc[m][n][r] + bv;
                    s += v / (1.f + __expf(-v));
                }
            s += __shfl_xor(s, 16);
            s += __shfl_xor(s, 32);
            if (kq == 0)
                ph[((size_t)bz * L_ + lwin) * H_ + n0 + cloc] = s * (1.f / 128.f);
        }
    }
}

// ==================== fallback 128^2 path (round-1, verified) ====================
__device__ __forceinline__ void stage_bf16_gload(const u16* gtile, int ld, u16* Ts,
                                                 int w, int lane) {
    const int r_in = lane >> 3;
    const int c0   = (lane & 7) << 3;
#pragma unroll
    for (int j = 0; j < 4; ++j) {
        int row = ((w << 2) + j) * 8 + r_in;
        const u16* g = gtile + (size_t)row * ld + c0;
        u16* l = Ts + (((w << 2) + j) << 9);
        gload16(g, l);
    }
}

__device__ __forceinline__ void stage_f32_cvt(const float* gtile, int ld, u16* Ts, int t) {
#pragma unroll
    for (int i = 0; i < 8; ++i) {
        int slot = t + (i << 8);
        int row  = slot >> 4;
        int c4   = (slot & 15) << 2;
        float4 v = *reinterpret_cast<const float4*>(gtile + (size_t)row * ld + c4);
        ushort4 o;
        o.x = f2bf(v.x); o.y = f2bf(v.y); o.z = f2bf(v.z); o.w = f2bf(v.w);
        *reinterpret_cast<ushort4*>(&Ts[row * 64 + c4]) = o;
    }
}

__device__ __forceinline__ void mfma_tile(const u16* As, const u16* Bs,
                                          f32x4 (&acc)[4][4], int wr, int wc, int lane) {
#pragma unroll
    for (int ks = 0; ks < 2; ++ks) {
        const int ko = (ks << 5) + ((lane >> 4) << 3);
        bf16x8 a[4], b[4];
#pragma unroll
        for (int m = 0; m < 4; ++m)
            a[m] = *reinterpret_cast<const bf16x8*>(&As[(wr * 64 + m * 16 + (lane & 15)) * 64 + ko]);
#pragma unroll
        for (int n = 0; n < 4; ++n)
            b[n] = *reinterpret_cast<const bf16x8*>(&Bs[(wc * 64 + n * 16 + (lane & 15)) * 64 + ko]);
#pragma unroll
        for (int m = 0; m < 4; ++m)
#pragma unroll
            for (int n = 0; n < 4; ++n)
                acc[m][n] = __builtin_amdgcn_mfma_f32_16x16x32_bf16(a[m], b[n], acc[m][n], 0, 0, 0);
    }
}

__global__ __launch_bounds__(256, 2) void k_gemm1(const float* __restrict__ x,
                                                  const u16* __restrict__ Wqb,
                                                  const float* __restrict__ bq,
                                                  u16* __restrict__ qb) {
    __shared__ u16 As[128 * 64];
    __shared__ u16 Bs[128 * 64];
    const int t = threadIdx.x, w = t >> 6, lane = t & 63;
    const int wr = w >> 1, wc = w & 1;
    const int m0 = blockIdx.y * 128;
    const int n0 = blockIdx.x * 128;

    f32x4 acc[4][4];
#pragma unroll
    for (int m = 0; m < 4; ++m)
#pragma unroll
        for (int n = 0; n < 4; ++n) acc[m][n] = (f32x4){0.f, 0.f, 0.f, 0.f};

    for (int kt = 0; kt < C_ / 64; ++kt) {
        stage_f32_cvt(x + (size_t)m0 * C_ + kt * 64, C_, As, t);
        stage_bf16_gload(Wqb + (size_t)n0 * C_ + kt * 64, C_, Bs, w, lane);
        __syncthreads();
        mfma_tile(As, Bs, acc, wr, wc, lane);
        __syncthreads();
    }

    const int r0 = m0 + wr * 64 + ((lane >> 4) << 2);
    const int cb = n0 + wc * 64 + (lane & 15);
#pragma unroll
    for (int n = 0; n < 4; ++n) {
        int c = cb + n * 16;
        float bb = bq[c];
#pragma unroll
        for (int m = 0; m < 4; ++m)
#pragma unroll
            for (int r = 0; r < 4; ++r)
                qb[(size_t)(r0 + m * 16 + r) * C_ + c] = f2bf(acc[m][n][r] + bb);
    }
}

template <bool BPRE>
__global__ __launch_bounds__(256, 2) void k_gemm2(const u16* __restrict__ qb,
                                                  const u16* __restrict__ W0b,
                                                  const float* __restrict__ W0f,
                                                  const float* __restrict__ b0,
                                                  float* __restrict__ ph) {
    __shared__ u16 As[128 * 64];
    __shared__ u16 Bs[128 * 64];
    __shared__ float Ps[2][128];
    const int t = threadIdx.x, w = t >> 6, lane = t & 63;
    const int wr = w >> 1, wc = w & 1;
    const int b  = blockIdx.z;
    const int mt = blockIdx.y;
    const int n0 = blockIdx.x * 128;
    const u16* Abase = qb + ((size_t)b * T_ + mt * 128) * C_;

    f32x4 acc[4][4];
#pragma unroll
    for (int m = 0; m < 4; ++m)
#pragma unroll
        for (int n = 0; n < 4; ++n) acc[m][n] = (f32x4){0.f, 0.f, 0.f, 0.f};

    for (int kt = 0; kt < C_ / 64; ++kt) {
        stage_bf16_gload(Abase + kt * 64, C_, As, w, lane);
        if (BPRE)
            stage_bf16_gload(W0b + ((size_t)b * H_ + n0) * C_ + kt * 64, C_, Bs, w, lane);
        else
            stage_f32_cvt(W0f + ((size_t)b * H_ + n0) * C_ + kt * 64, C_, Bs, t);
        __syncthreads();
        mfma_tile(As, Bs, acc, wr, wc, lane);
        __syncthreads();
    }

    float s[4];
#pragma unroll
    for (int n = 0; n < 4; ++n) {
        int c = n0 + wc * 64 + n * 16 + (lane & 15);
        float bb = b0[b * H_ + c];
        float sum = 0.f;
#pragma unroll
        for (int m = 0; m < 4; ++m)
#pragma unroll
            for (int r = 0; r < 4; ++r) {
                float v = acc[m][n][r] + bb;
                sum += v / (1.f + __expf(-v));
            }
        sum += __shfl_xor(sum, 16);
        sum += __shfl_xor(sum, 32);
        s[n] = sum;
    }
    if (lane < 16) {
#pragma unroll
        for (int n = 0; n < 4; ++n) Ps[wr][wc * 64 + n * 16 + lane] = s[n];
    }
    __syncthreads();
    if (t < 128)
        ph[((size_t)b * L_ + mt) * H_ + n0 + t] = (Ps[0][t] + Ps[1][t]) * (1.f / 128.f);
}

// ---------- pass 3a: pooled = pooled_h @ W1[b]^T + b1 ----------
__global__ __launch_bounds__(256) void k_3a(const float* __restrict__ ph,
                                            const float* __restrict__ W1,
                                            const float* __restrict__ b1,
                                            float* __restrict__ pooled) {
    const int t = threadIdx.x, w = t >> 6, lane = t & 63;
    const int b  = blockIdx.y;
    const int cb = blockIdx.x * 16 + w * 4;

    float acc[4][16];
#pragma unroll
    for (int g = 0; g < 4; ++g)
#pragma unroll
        for (int l = 0; l < 16; ++l) acc[g][l] = 0.f;

    for (int i = 0; i < H_ / 256; ++i) {
        int h0 = i * 256 + lane * 4;
        float4 wv[4];
#pragma unroll
        for (int g = 0; g < 4; ++g)
            wv[g] = *reinterpret_cast<const float4*>(W1 + ((size_t)b * C_ + cb + g) * H_ + h0);
#pragma unroll
        for (int l = 0; l < 16; ++l) {
            float4 pv = *reinterpret_cast<const float4*>(ph + ((size_t)b * L_ + l) * H_ + h0);
#pragma unroll
            for (int g = 0; g < 4; ++g)
                acc[g][l] += wv[g].x * pv.x + wv[g].y * pv.y + wv[g].z * pv.z + wv[g].w * pv.w;
        }
    }
#pragma unroll
    for (int g = 0; g < 4; ++g)
#pragma unroll
        for (int l = 0; l < 16; ++l) acc[g][l] = wave_sum(acc[g][l]);

    if (lane < 16) {
#pragma unroll
        for (int g = 0; g < 4; ++g)
            pooled[((size_t)b * L_ + lane) * C_ + cb + g] = acc[g][lane] + b1[b * C_ + cb + g];
    }
}

// ---------- pass 3b: out = pooled @ Wo^T + bo ----------
__global__ __launch_bounds__(256) void k_3b(const float* __restrict__ pooled,
                                            const float* __restrict__ Wo,
                                            const float* __restrict__ bo,
                                            float* __restrict__ out) {
    __shared__ __align__(16) float ps[4 * 768];
    const int t = threadIdx.x, w = t >> 6, lane = t & 63;
    const int rr0 = blockIdx.x * 4;

    for (int idx = t; idx < 4 * 768; idx += 256)
        ps[idx] = pooled[(size_t)rr0 * 768 + idx];
    __syncthreads();

    for (int d = w; d < 768; d += 4) {
        float a0 = 0.f, a1 = 0.f, a2 = 0.f, a3 = 0.f;
#pragma unroll
        for (int i = 0; i < 3; ++i) {
            int c = i * 256 + lane * 4;
            float4 wv = *reinterpret_cast<const float4*>(Wo + (size_t)d * 768 + c);
            float4 p0 = *reinterpret_cast<const float4*>(&ps[0 * 768 + c]);
            float4 p1 = *reinterpret_cast<const float4*>(&ps[1 * 768 + c]);
            float4 p2 = *reinterpret_cast<const float4*>(&ps[2 * 768 + c]);
            float4 p3 = *reinterpret_cast<const float4*>(&ps[3 * 768 + c]);
            a0 += wv.x * p0.x + wv.y * p0.y + wv.z * p0.z + wv.w * p0.w;
            a1 += wv.x * p1.x + wv.y * p1.y + wv.z * p1.z + wv.w * p1.w;
            a2 += wv.x * p2.x + wv.y * p2.y + wv.z * p2.z + wv.w * p2.w;
            a3 += wv.x * p3.x + wv.y * p3.y + wv.z * p3.z + wv.w * p3.w;
        }
        a0 = wave_sum(a0); a1 = wave_sum(a1); a2 = wave_sum(a2); a3 = wave_sum(a3);
        if (lane == 0) {
            float bb = bo[d];
            out[(size_t)(rr0 + 0) * 768 + d] = a0 + bb;
            out[(size_t)(rr0 + 1) * 768 + d] = a1 + bb;
            out[(size_t)(rr0 + 2) * 768 + d] = a2 + bb;
            out[(size_t)(rr0 + 3) * 768 + d] = a3 + bb;
        }
    }
}

extern "C" void kernel_launch(void* const* d_in, const int* in_sizes, int n_in,
                              void* d_out, int out_size, void* d_ws, size_t ws_size,
                              hipStream_t stream) {
    const float* x  = (const float*)d_in[0];
    const float* Wq = (const float*)d_in[1];
    const float* bq = (const float*)d_in[2];
    const float* W0 = (const float*)d_in[3];
    const float* b0 = (const float*)d_in[4];
    const float* W1 = (const float*)d_in[5];
    const float* b1 = (const float*)d_in[6];
    const float* Wo = (const float*)d_in[7];
    const float* bo = (const float*)d_in[8];
    float* out = (float*)d_out;

    char* p = (char*)d_ws;
    size_t off = 0;
    auto carve = [&](size_t bytes) -> char* {
        char* r = p + off;
        off += (bytes + 255) & ~(size_t)255;
        return r;
    };
    u16*   qb     = (u16*)carve((size_t)B_ * T_ * C_ * 2);   // 100.7 MB
    u16*   Wqb    = (u16*)carve((size_t)C_ * C_ * 2);        // 1.2 MB
    float* ph     = (float*)carve((size_t)B_ * L_ * H_ * 4); // 3.1 MB
    float* pooled = (float*)carve((size_t)B_ * L_ * C_ * 4); // 1.6 MB

    const size_t w0b_bytes = (size_t)B_ * H_ * C_ * 2;       // 75.5 MB (fallback only)

    if (off <= ws_size) {
        // fast path: fused-cvt 256^2 GEMMs; only Wq needs a pre-cvt (1.2 MB)
        k_cvt<<<dim3(64), 256, 0, stream>>>(Wq, Wqb, C_ * C_ / 4);
        k_gemmF<0><<<dim3(C_ / 256, (B_ * T_) / 256), 512, 0, stream>>>(Wqb, x, bq, qb, nullptr);
        k_gemmF<1><<<dim3(H_ / 256, T_ / 256, B_), 512, 0, stream>>>(qb, W0, b0, nullptr, ph);
    } else {
        // fallback: round-1 verified 128^2 path
        u16* W0b = nullptr;
        if (off + w0b_bytes <= ws_size) W0b = (u16*)carve(w0b_bytes);

        k_cvt<<<dim3(64), 256, 0, stream>>>(Wq, Wqb, C_ * C_ / 4);
        if (W0b)
            k_cvt<<<dim3(2048), 256, 0, stream>>>(W0, W0b, B_ * H_ * C_ / 4);
        k_gemm1<<<dim3(C_ / 128, (B_ * T_) / 128), 256, 0, stream>>>(x, Wqb, bq, qb);
        if (W0b)
            k_gemm2<true><<<dim3(H_ / 128, L_, B_), 256, 0, stream>>>(qb, W0b, nullptr, b0, ph);
        else
            k_gemm2<false><<<dim3(H_ / 128, L_, B_), 256, 0, stream>>>(qb, nullptr, W0, b0, ph);
    }

    k_3a<<<dim3(C_ / 16, B_), 256, 0, stream>>>(ph, W1, b1, pooled);
    k_3b<<<dim3(B_ * L_ / 4), 256, 0, stream>>>(pooled, Wo, bo, out);
}

// Round 7
// 619.887 us; speedup vs baseline: 1.2061x; 1.2061x over previous
//
#include <hip/hip_runtime.h>
#include <stdint.h>

#define B_ 32
#define T_ 2048
#define C_ 768
#define H_ 1536
#define L_ 16

typedef unsigned short u16;
typedef __bf16 bf16x8 __attribute__((ext_vector_type(8)));
typedef float f32x4 __attribute__((ext_vector_type(4)));

__device__ __forceinline__ u16 f2bf(float f) {
    union { float f; uint32_t u; } v; v.f = f;
    uint32_t r = (v.u + 0x7fffu + ((v.u >> 16) & 1u)) >> 16;
    return (u16)r;
}

__device__ __forceinline__ float wave_sum(float v) {
    v += __shfl_xor(v, 1);  v += __shfl_xor(v, 2);  v += __shfl_xor(v, 4);
    v += __shfl_xor(v, 8);  v += __shfl_xor(v, 16); v += __shfl_xor(v, 32);
    return v;
}

__global__ void k_cvt(const float* __restrict__ in, u16* __restrict__ out, int n4) {
    int stride = gridDim.x * blockDim.x;
    for (int i = blockIdx.x * blockDim.x + threadIdx.x; i < n4; i += stride) {
        float4 v = reinterpret_cast<const float4*>(in)[i];
        ushort4 o;
        o.x = f2bf(v.x); o.y = f2bf(v.y); o.z = f2bf(v.z); o.w = f2bf(v.w);
        reinterpret_cast<ushort4*>(out)[i] = o;
    }
}

// one streaming dispatch converting up to 3 (src,dst,len4) segments
__global__ void k_cvt_multi(const float* __restrict__ s0, u16* __restrict__ d0, int n0,
                            const float* __restrict__ s1, u16* __restrict__ d1, int n1,
                            const float* __restrict__ s2, u16* __restrict__ d2, int n2) {
    int stride = gridDim.x * blockDim.x;
    int total = n0 + n1 + n2;
    for (int i = blockIdx.x * blockDim.x + threadIdx.x; i < total; i += stride) {
        const float* s; u16* d; int j = i;
        if (j < n0) { s = s0; d = d0; }
        else if ((j -= n0) < n1) { s = s1; d = d1; }
        else { j -= n1; s = s2; d = d2; }
        float4 v = reinterpret_cast<const float4*>(s)[j];
        ushort4 o;
        o.x = f2bf(v.x); o.y = f2bf(v.y); o.z = f2bf(v.z); o.w = f2bf(v.w);
        reinterpret_cast<ushort4*>(d)[j] = o;
    }
}

__device__ __forceinline__ void gload16(const u16* g, u16* l) {
    __builtin_amdgcn_global_load_lds((const __attribute__((address_space(1))) void*)g,
                                     (__attribute__((address_space(3))) void*)l, 16, 0, 0);
}

// ============ 256x256 bf16 GEMM — 2-region K-tile, wave-slip overlap (R5) ============
template <int EPI>
__global__ __launch_bounds__(512, 2) void k_gemm8(const u16* __restrict__ Aall,
                                                  const u16* __restrict__ Ball,
                                                  const float* __restrict__ biasall,
                                                  u16* __restrict__ qout,
                                                  float* __restrict__ ph) {
    __shared__ u16 sm[65536];   // [buf2][A/B][half2][128*64] = 128 KiB
    const int t = threadIdx.x;
    const int w = t >> 6, lane = t & 63;
    const int wr = w >> 2, wc = w & 3;
    const int l15 = lane & 15, kq = lane >> 4, cx = lane & 7;

    // T1: bijective XCD-aware block remap (nwg % 8 == 0 for both EPIs)
    const int gx = gridDim.x, gy = gridDim.y;
    const int nwg = gx * gy * gridDim.z;
    int flat = blockIdx.x + gx * (blockIdx.y + gy * blockIdx.z);
    if ((nwg & 7) == 0) flat = (flat & 7) * (nwg >> 3) + (flat >> 3);
    const int bx = flat % gx;
    const int tmp = flat / gx;
    const int by = tmp % gy;
    const int bz = tmp / gy;

    const int n0 = bx * 256;
    const int m0 = by * 256;
    const u16* A; const u16* Bm; const float* bias;
    if constexpr (EPI == 0) {
        A = Aall + (size_t)m0 * C_;
        Bm = Ball + (size_t)n0 * C_;
        bias = biasall + n0;
    } else {
        A = Aall + ((size_t)bz * T_ + m0) * C_;
        Bm = Ball + ((size_t)bz * H_ + n0) * C_;
        bias = biasall + (size_t)bz * H_ + n0;
    }

    // staging: per half-tile (128 rows x 64 k), wave w writes rows [w*16, w*16+16)
    // via 2 gloads; linear LDS dest; inverse-swizzled global col (T2, rule #21).
    const int rl = (w << 4) + (lane >> 3);
    const int cs = (((lane & 7) ^ ((lane >> 3) & 7)) << 3);
    const int ldst = (w << 10);

    auto stA = [&](int kt, int h) {
        const u16* g = A + (size_t)(h * 128 + rl) * C_ + kt * 64 + cs;
        u16* l = sm + (kt & 1) * 32768 + h * 8192 + ldst;
        gload16(g, l);
        gload16(g + 8 * C_, l + 512);
    };
    auto stB = [&](int kt, int h) {
        const u16* g = Bm + (size_t)(h * 128 + rl) * C_ + kt * 64 + cs;
        u16* l = sm + (kt & 1) * 32768 + 16384 + h * 8192 + ldst;
        gload16(g, l);
        gload16(g + 8 * C_, l + 512);
    };

    f32x4 acc[8][4];
#pragma unroll
    for (int m = 0; m < 8; ++m)
#pragma unroll
        for (int n = 0; n < 4; ++n) acc[m][n] = (f32x4){0.f, 0.f, 0.f, 0.f};

    bf16x8 a0[4][2], a1[4][2], bfr[2][2];

    // per-lane LDS read bases; in-loop reads are base + literal offsets
    const int koff0 = ((kq ^ cx) << 3);
    const int koff1 = (((4 + kq) ^ cx) << 3);
    const u16* vA0 = sm + wr * 8192 + l15 * 64 + koff0;
    const u16* vA1 = sm + wr * 8192 + l15 * 64 + koff1;
    const u16* vB0 = sm + 16384 + (wc >> 1) * 8192 + (wc & 1) * 4096 + l15 * 64 + koff0;
    const u16* vB1 = sm + 16384 + (wc >> 1) * 8192 + (wc & 1) * 4096 + l15 * 64 + koff1;

    auto rdAB0 = [&](int bt) {
        const u16* A0 = vA0 + bt * 32768;
        const u16* A1 = vA1 + bt * 32768;
        const u16* B0 = vB0 + bt * 32768;
        const u16* B1 = vB1 + bt * 32768;
        bfr[0][0] = *reinterpret_cast<const bf16x8*>(B0);
        bfr[1][0] = *reinterpret_cast<const bf16x8*>(B0 + 1024);
        a0[0][0] = *reinterpret_cast<const bf16x8*>(A0);
        a0[1][0] = *reinterpret_cast<const bf16x8*>(A0 + 1024);
        a0[2][0] = *reinterpret_cast<const bf16x8*>(A0 + 2048);
        a0[3][0] = *reinterpret_cast<const bf16x8*>(A0 + 3072);
        bfr[0][1] = *reinterpret_cast<const bf16x8*>(B1);
        bfr[1][1] = *reinterpret_cast<const bf16x8*>(B1 + 1024);
        a0[0][1] = *reinterpret_cast<const bf16x8*>(A1);
        a0[1][1] = *reinterpret_cast<const bf16x8*>(A1 + 1024);
        a0[2][1] = *reinterpret_cast<const bf16x8*>(A1 + 2048);
        a0[3][1] = *reinterpret_cast<const bf16x8*>(A1 + 3072);
    };
    auto rdA1 = [&](int bt) {
        const u16* A0 = vA0 + bt * 32768 + 4096;
        const u16* A1 = vA1 + bt * 32768 + 4096;
        a1[0][0] = *reinterpret_cast<const bf16x8*>(A0);
        a1[1][0] = *reinterpret_cast<const bf16x8*>(A0 + 1024);
        a1[2][0] = *reinterpret_cast<const bf16x8*>(A0 + 2048);
        a1[3][0] = *reinterpret_cast<const bf16x8*>(A0 + 3072);
        a1[0][1] = *reinterpret_cast<const bf16x8*>(A1);
        a1[1][1] = *reinterpret_cast<const bf16x8*>(A1 + 1024);
        a1[2][1] = *reinterpret_cast<const bf16x8*>(A1 + 2048);
        a1[3][1] = *reinterpret_cast<const bf16x8*>(A1 + 3072);
    };
    auto rdB1 = [&](int bt) {
        const u16* B0 = vB0 + bt * 32768 + 2048;
        const u16* B1 = vB1 + bt * 32768 + 2048;
        bfr[0][0] = *reinterpret_cast<const bf16x8*>(B0);
        bfr[1][0] = *reinterpret_cast<const bf16x8*>(B0 + 1024);
        bfr[0][1] = *reinterpret_cast<const bf16x8*>(B1);
        bfr[1][1] = *reinterpret_cast<const bf16x8*>(B1 + 1024);
    };
    auto mma16 = [&](bf16x8 (&a)[4][2], int mq, int qn) {
        __builtin_amdgcn_s_setprio(1);
#pragma unroll
        for (int ks = 0; ks < 2; ++ks)
#pragma unroll
            for (int mm = 0; mm < 4; ++mm)
#pragma unroll
                for (int nn = 0; nn < 2; ++nn)
                    acc[mq * 4 + mm][qn * 2 + nn] = __builtin_amdgcn_mfma_f32_16x16x32_bf16(
                        a[mm][ks], bfr[nn][ks], acc[mq * 4 + mm][qn * 2 + nn], 0, 0, 0);
        __builtin_amdgcn_s_setprio(0);
    };

    auto ktile = [&](int kt, int bt) {
        // R1: frags {a0, a1, bfr(qn0)}; stage B(kt+1) both halves; 32 MFMA
        rdAB0(bt);
        rdA1(bt);
        if (kt + 1 < 12) { stB(kt + 1, 0); stB(kt + 1, 1); }
        mma16(a0, 0, 0);
        mma16(a1, 1, 0);
        __builtin_amdgcn_s_barrier();
        // R2: frags bfr(qn1); stage A(kt+2) both halves; 32 MFMA; counted vmcnt
        rdB1(bt);
        const bool st = (kt + 2 < 12);
        if (st) { stA(kt + 2, 0); stA(kt + 2, 1); }
        mma16(a0, 0, 1);
        mma16(a1, 1, 1);
        if (st) asm volatile("s_waitcnt vmcnt(4)" ::: "memory");
        else    asm volatile("s_waitcnt vmcnt(0)" ::: "memory");
        __builtin_amdgcn_s_barrier();
    };

    // prologue: tile0 (A+B) + tile1 A = 12 loads; vmcnt(4) -> tile0 landed.
    stA(0, 0); stA(0, 1); stB(0, 0); stB(0, 1);
    stA(1, 0); stA(1, 1);
    asm volatile("s_waitcnt vmcnt(4)" ::: "memory");
    __builtin_amdgcn_s_barrier();

#pragma unroll 1
    for (int ktb = 0; ktb < 12; ktb += 2) {
        ktile(ktb, 0);
        ktile(ktb + 1, 1);
    }

    if constexpr (EPI == 0) {
        // line-contiguous store bursts: per (m,r), the 4 n-stores cover one
        // full 128B line back-to-back -> write-combine
        const int colb = n0 + wc * 64 + l15;
        const int rowb = m0 + wr * 128 + (kq << 2);
        float bv[4];
#pragma unroll
        for (int n = 0; n < 4; ++n) bv[n] = bias[wc * 64 + n * 16 + l15];
#pragma unroll
        for (int m = 0; m < 8; ++m)
#pragma unroll
            for (int r = 0; r < 4; ++r) {
                size_t ro = (size_t)(rowb + m * 16 + r) * C_;
#pragma unroll
                for (int n = 0; n < 4; ++n)
                    qout[ro + colb + n * 16] = f2bf(acc[m][n][r] + bv[n]);
            }
    } else {
        const int lwin = by * 2 + wr;   // wave's 128 rows == one pooling window
#pragma unroll
        for (int n = 0; n < 4; ++n) {
            int cloc = wc * 64 + n * 16 + l15;
            float bv = bias[cloc];
            float s = 0.f;
#pragma unroll
            for (int m = 0; m < 8; ++m)
#pragma unroll
                for (int r = 0; r < 4; ++r) {
                    float v = acc[m][n][r] + bv;
                    s += v / (1.f + __expf(-v));
                }
            s += __shfl_xor(s, 16);
            s += __shfl_xor(s, 32);
            if (kq == 0)
                ph[((size_t)bz * L_ + lwin) * H_ + n0 + cloc] = s * (1.f / 128.f);
        }
    }
}

// ==================== fallback 128^2 path (round-1, verified) ====================
__device__ __forceinline__ void stage_bf16_gload(const u16* gtile, int ld, u16* Ts,
                                                 int w, int lane) {
    const int r_in = lane >> 3;
    const int c0   = (lane & 7) << 3;
#pragma unroll
    for (int j = 0; j < 4; ++j) {
        int row = ((w << 2) + j) * 8 + r_in;
        const u16* g = gtile + (size_t)row * ld + c0;
        u16* l = Ts + (((w << 2) + j) << 9);
        gload16(g, l);
    }
}

__device__ __forceinline__ void stage_f32_cvt(const float* gtile, int ld, u16* Ts, int t) {
#pragma unroll
    for (int i = 0; i < 8; ++i) {
        int slot = t + (i << 8);
        int row  = slot >> 4;
        int c4   = (slot & 15) << 2;
        float4 v = *reinterpret_cast<const float4*>(gtile + (size_t)row * ld + c4);
        ushort4 o;
        o.x = f2bf(v.x); o.y = f2bf(v.y); o.z = f2bf(v.z); o.w = f2bf(v.w);
        *reinterpret_cast<ushort4*>(&Ts[row * 64 + c4]) = o;
    }
}

__device__ __forceinline__ void mfma_tile(const u16* As, const u16* Bs,
                                          f32x4 (&acc)[4][4], int wr, int wc, int lane) {
#pragma unroll
    for (int ks = 0; ks < 2; ++ks) {
        const int ko = (ks << 5) + ((lane >> 4) << 3);
        bf16x8 a[4], b[4];
#pragma unroll
        for (int m = 0; m < 4; ++m)
            a[m] = *reinterpret_cast<const bf16x8*>(&As[(wr * 64 + m * 16 + (lane & 15)) * 64 + ko]);
#pragma unroll
        for (int n = 0; n < 4; ++n)
            b[n] = *reinterpret_cast<const bf16x8*>(&Bs[(wc * 64 + n * 16 + (lane & 15)) * 64 + ko]);
#pragma unroll
        for (int m = 0; m < 4; ++m)
#pragma unroll
            for (int n = 0; n < 4; ++n)
                acc[m][n] = __builtin_amdgcn_mfma_f32_16x16x32_bf16(a[m], b[n], acc[m][n], 0, 0, 0);
    }
}

__global__ __launch_bounds__(256, 2) void k_gemm1(const float* __restrict__ x,
                                                  const u16* __restrict__ Wqb,
                                                  const float* __restrict__ bq,
                                                  u16* __restrict__ qb) {
    __shared__ u16 As[128 * 64];
    __shared__ u16 Bs[128 * 64];
    const int t = threadIdx.x, w = t >> 6, lane = t & 63;
    const int wr = w >> 1, wc = w & 1;
    const int m0 = blockIdx.y * 128;
    const int n0 = blockIdx.x * 128;

    f32x4 acc[4][4];
#pragma unroll
    for (int m = 0; m < 4; ++m)
#pragma unroll
        for (int n = 0; n < 4; ++n) acc[m][n] = (f32x4){0.f, 0.f, 0.f, 0.f};

    for (int kt = 0; kt < C_ / 64; ++kt) {
        stage_f32_cvt(x + (size_t)m0 * C_ + kt * 64, C_, As, t);
        stage_bf16_gload(Wqb + (size_t)n0 * C_ + kt * 64, C_, Bs, w, lane);
        __syncthreads();
        mfma_tile(As, Bs, acc, wr, wc, lane);
        __syncthreads();
    }

    const int r0 = m0 + wr * 64 + ((lane >> 4) << 2);
    const int cb = n0 + wc * 64 + (lane & 15);
#pragma unroll
    for (int n = 0; n < 4; ++n) {
        int c = cb + n * 16;
        float bb = bq[c];
#pragma unroll
        for (int m = 0; m < 4; ++m)
#pragma unroll
            for (int r = 0; r < 4; ++r)
                qb[(size_t)(r0 + m * 16 + r) * C_ + c] = f2bf(acc[m][n][r] + bb);
    }
}

template <bool BPRE>
__global__ __launch_bounds__(256, 2) void k_gemm2(const u16* __restrict__ qb,
                                                  const u16* __restrict__ W0b,
                                                  const float* __restrict__ W0f,
                                                  const float* __restrict__ b0,
                                                  float* __restrict__ ph) {
    __shared__ u16 As[128 * 64];
    __shared__ u16 Bs[128 * 64];
    __shared__ float Ps[2][128];
    const int t = threadIdx.x, w = t >> 6, lane = t & 63;
    const int wr = w >> 1, wc = w & 1;
    const int b  = blockIdx.z;
    const int mt = blockIdx.y;
    const int n0 = blockIdx.x * 128;
    const u16* Abase = qb + ((size_t)b * T_ + mt * 128) * C_;

    f32x4 acc[4][4];
#pragma unroll
    for (int m = 0; m < 4; ++m)
#pragma unroll
        for (int n = 0; n < 4; ++n) acc[m][n] = (f32x4){0.f, 0.f, 0.f, 0.f};

    for (int kt = 0; kt < C_ / 64; ++kt) {
        stage_bf16_gload(Abase + kt * 64, C_, As, w, lane);
        if (BPRE)
            stage_bf16_gload(W0b + ((size_t)b * H_ + n0) * C_ + kt * 64, C_, Bs, w, lane);
        else
            stage_f32_cvt(W0f + ((size_t)b * H_ + n0) * C_ + kt * 64, C_, Bs, t);
        __syncthreads();
        mfma_tile(As, Bs, acc, wr, wc, lane);
        __syncthreads();
    }

    float s[4];
#pragma unroll
    for (int n = 0; n < 4; ++n) {
        int c = n0 + wc * 64 + n * 16 + (lane & 15);
        float bb = b0[b * H_ + c];
        float sum = 0.f;
#pragma unroll
        for (int m = 0; m < 4; ++m)
#pragma unroll
            for (int r = 0; r < 4; ++r) {
                float v = acc[m][n][r] + bb;
                sum += v / (1.f + __expf(-v));
            }
        sum += __shfl_xor(sum, 16);
        sum += __shfl_xor(sum, 32);
        s[n] = sum;
    }
    if (lane < 16) {
#pragma unroll
        for (int n = 0; n < 4; ++n) Ps[wr][wc * 64 + n * 16 + lane] = s[n];
    }
    __syncthreads();
    if (t < 128)
        ph[((size_t)b * L_ + mt) * H_ + n0 + t] = (Ps[0][t] + Ps[1][t]) * (1.f / 128.f);
}

// ---------- pass 3a: pooled = pooled_h @ W1[b]^T + b1 ----------
__global__ __launch_bounds__(256) void k_3a(const float* __restrict__ ph,
                                            const float* __restrict__ W1,
                                            const float* __restrict__ b1,
                                            float* __restrict__ pooled) {
    const int t = threadIdx.x, w = t >> 6, lane = t & 63;
    const int b  = blockIdx.y;
    const int cb = blockIdx.x * 16 + w * 4;

    float acc[4][16];
#pragma unroll
    for (int g = 0; g < 4; ++g)
#pragma unroll
        for (int l = 0; l < 16; ++l) acc[g][l] = 0.f;

    for (int i = 0; i < H_ / 256; ++i) {
        int h0 = i * 256 + lane * 4;
        float4 wv[4];
#pragma unroll
        for (int g = 0; g < 4; ++g)
            wv[g] = *reinterpret_cast<const float4*>(W1 + ((size_t)b * C_ + cb + g) * H_ + h0);
#pragma unroll
        for (int l = 0; l < 16; ++l) {
            float4 pv = *reinterpret_cast<const float4*>(ph + ((size_t)b * L_ + l) * H_ + h0);
#pragma unroll
            for (int g = 0; g < 4; ++g)
                acc[g][l] += wv[g].x * pv.x + wv[g].y * pv.y + wv[g].z * pv.z + wv[g].w * pv.w;
        }
    }
#pragma unroll
    for (int g = 0; g < 4; ++g)
#pragma unroll
        for (int l = 0; l < 16; ++l) acc[g][l] = wave_sum(acc[g][l]);

    if (lane < 16) {
#pragma unroll
        for (int g = 0; g < 4; ++g)
            pooled[((size_t)b * L_ + lane) * C_ + cb + g] = acc[g][lane] + b1[b * C_ + cb + g];
    }
}

// ---------- pass 3b: out = pooled @ Wo^T + bo ----------
__global__ __launch_bounds__(256) void k_3b(const float* __restrict__ pooled,
                                            const float* __restrict__ Wo,
                                            const float* __restrict__ bo,
                                            float* __restrict__ out) {
    __shared__ __align__(16) float ps[4 * 768];
    const int t = threadIdx.x, w = t >> 6, lane = t & 63;
    const int rr0 = blockIdx.x * 4;

    for (int idx = t; idx < 4 * 768; idx += 256)
        ps[idx] = pooled[(size_t)rr0 * 768 + idx];
    __syncthreads();

    for (int d = w; d < 768; d += 4) {
        float a0 = 0.f, a1 = 0.f, a2 = 0.f, a3 = 0.f;
#pragma unroll
        for (int i = 0; i < 3; ++i) {
            int c = i * 256 + lane * 4;
            float4 wv = *reinterpret_cast<const float4*>(Wo + (size_t)d * 768 + c);
            float4 p0 = *reinterpret_cast<const float4*>(&ps[0 * 768 + c]);
            float4 p1 = *reinterpret_cast<const float4*>(&ps[1 * 768 + c]);
            float4 p2 = *reinterpret_cast<const float4*>(&ps[2 * 768 + c]);
            float4 p3 = *reinterpret_cast<const float4*>(&ps[3 * 768 + c]);
            a0 += wv.x * p0.x + wv.y * p0.y + wv.z * p0.z + wv.w * p0.w;
            a1 += wv.x * p1.x + wv.y * p1.y + wv.z * p1.z + wv.w * p1.w;
            a2 += wv.x * p2.x + wv.y * p2.y + wv.z * p2.z + wv.w * p2.w;
            a3 += wv.x * p3.x + wv.y * p3.y + wv.z * p3.z + wv.w * p3.w;
        }
        a0 = wave_sum(a0); a1 = wave_sum(a1); a2 = wave_sum(a2); a3 = wave_sum(a3);
        if (lane == 0) {
            float bb = bo[d];
            out[(size_t)(rr0 + 0) * 768 + d] = a0 + bb;
            out[(size_t)(rr0 + 1) * 768 + d] = a1 + bb;
            out[(size_t)(rr0 + 2) * 768 + d] = a2 + bb;
            out[(size_t)(rr0 + 3) * 768 + d] = a3 + bb;
        }
    }
}

extern "C" void kernel_launch(void* const* d_in, const int* in_sizes, int n_in,
                              void* d_out, int out_size, void* d_ws, size_t ws_size,
                              hipStream_t stream) {
    const float* x  = (const float*)d_in[0];
    const float* Wq = (const float*)d_in[1];
    const float* bq = (const float*)d_in[2];
    const float* W0 = (const float*)d_in[3];
    const float* b0 = (const float*)d_in[4];
    const float* W1 = (const float*)d_in[5];
    const float* b1 = (const float*)d_in[6];
    const float* Wo = (const float*)d_in[7];
    const float* bo = (const float*)d_in[8];
    float* out = (float*)d_out;

    char* p = (char*)d_ws;
    size_t off = 0;
    auto carve = [&](size_t bytes) -> char* {
        char* r = p + off;
        off += (bytes + 255) & ~(size_t)255;
        return r;
    };
    u16*   qb     = (u16*)carve((size_t)B_ * T_ * C_ * 2);   // 100.7 MB
    u16*   Wqb    = (u16*)carve((size_t)C_ * C_ * 2);        // 1.2 MB
    float* ph     = (float*)carve((size_t)B_ * L_ * H_ * 4); // 3.1 MB
    float* pooled = (float*)carve((size_t)B_ * L_ * C_ * 4); // 1.6 MB

    const size_t xb_bytes  = (size_t)B_ * T_ * C_ * 2;       // 100.7 MB
    const size_t w0b_bytes = (size_t)B_ * H_ * C_ * 2;       // 75.5 MB

    const int n4x  = B_ * T_ * C_ / 4;
    const int n4wq = C_ * C_ / 4;
    const int n4w0 = B_ * H_ * C_ / 4;

    if (off + xb_bytes + w0b_bytes <= ws_size) {
        // fastest path: all conversions in ONE streaming dispatch, no aliasing
        u16* xb  = (u16*)carve(xb_bytes);
        u16* W0b = (u16*)carve(w0b_bytes);
        k_cvt_multi<<<dim3(2048), 256, 0, stream>>>(x, xb, n4x, Wq, Wqb, n4wq, W0, W0b, n4w0);
        k_gemm8<0><<<dim3(C_ / 256, (B_ * T_) / 256), 512, 0, stream>>>(xb, Wqb, bq, qb, nullptr);
        k_gemm8<1><<<dim3(H_ / 256, T_ / 256, B_), 512, 0, stream>>>(qb, W0b, b0, nullptr, ph);
    } else if (off + xb_bytes <= ws_size) {
        // R5 path: xb/W0b alias; W0 converts after gemm0
        u16* xb  = (u16*)carve(xb_bytes);
        u16* W0b = xb;
        k_cvt_multi<<<dim3(2048), 256, 0, stream>>>(x, xb, n4x, Wq, Wqb, n4wq,
                                                    nullptr, nullptr, 0);
        k_gemm8<0><<<dim3(C_ / 256, (B_ * T_) / 256), 512, 0, stream>>>(xb, Wqb, bq, qb, nullptr);
        k_cvt<<<dim3(2048), 256, 0, stream>>>(W0, W0b, n4w0);
        k_gemm8<1><<<dim3(H_ / 256, T_ / 256, B_), 512, 0, stream>>>(qb, W0b, b0, nullptr, ph);
    } else {
        // fallback: round-1 verified 128^2 path
        u16* W0b = nullptr;
        if (off + w0b_bytes <= ws_size) W0b = (u16*)carve(w0b_bytes);

        k_cvt<<<dim3(64), 256, 0, stream>>>(Wq, Wqb, n4wq);
        if (W0b)
            k_cvt<<<dim3(2048), 256, 0, stream>>>(W0, W0b, n4w0);
        k_gemm1<<<dim3(C_ / 128, (B_ * T_) / 128), 256, 0, stream>>>(x, Wqb, bq, qb);
        if (W0b)
            k_gemm2<true><<<dim3(H_ / 128, L_, B_), 256, 0, stream>>>(qb, W0b, nullptr, b0, ph);
        else
            k_gemm2<false><<<dim3(H_ / 128, L_, B_), 256, 0, stream>>>(qb, nullptr, W0, b0, ph);
    }

    k_3a<<<dim3(C_ / 16, B_), 256, 0, stream>>>(ph, W1, b1, pooled);
    k_3b<<<dim3(B_ * L_ / 4), 256, 0, stream>>>(pooled, Wo, bo, out);
}